// Round 10
// baseline (866.021 us; speedup 1.0000x reference)
//
#include <hip/hip_runtime.h>
#include <hip/hip_bf16.h>
#include <cstdio>

// ---------------------------------------------------------------- types
typedef __bf16 bf16x4 __attribute__((ext_vector_type(4)));
typedef __bf16 bf16x8 __attribute__((ext_vector_type(8)));
typedef float  f32x4  __attribute__((ext_vector_type(4)));

#define NTOK 12608   // B*S = 64*197
#define DMODEL 768
#define SEQ 197

__device__ __forceinline__ float b2f(__bf16 v) { return (float)v; }

// fast GELU (tanh form, one v_exp_f32; |err| vs exact erf-GELU < ~3e-4)
__device__ __forceinline__ float gelu_f(float x) {
    float y = 1.5957691216f * (x + 0.044715f * x * x * x);
    float e = __expf(y);
    float t = 1.f - 2.f / (e + 1.f);
    return 0.5f * x * (1.f + t);
}

__device__ __forceinline__ void gload16(const void* src, void* dst) {
    __builtin_amdgcn_global_load_lds(
        (const __attribute__((address_space(1))) void*)src,
        (__attribute__((address_space(3))) void*)dst,
        16, 0, 0);
}

// ---------------------------------------------------------------- f32 -> bf16 convert (all 6 weights, one launch)
struct CvtArgs {
    const float* src[6];
    __bf16* dst[6];
    int n4[6];
};
__global__ __launch_bounds__(256) void cvt_all_k(CvtArgs a)
{
#pragma unroll
    for (int t = 0; t < 6; ++t) {
        const float4* in = (const float4*)a.src[t];
        bf16x4* out = (bf16x4*)a.dst[t];
        const int n4 = a.n4[t];
        for (int i = blockIdx.x * 256 + threadIdx.x; i < n4; i += gridDim.x * 256) {
            float4 v = in[i];
            bf16x4 o;
            o[0] = (__bf16)v.x; o[1] = (__bf16)v.y; o[2] = (__bf16)v.z; o[3] = (__bf16)v.w;
            out[i] = o;
        }
    }
}

// ---------------------------------------------------------------- LayerNorm (f32 in -> bf16 out), 1 wave/row
__global__ __launch_bounds__(256) void ln_k(const float* __restrict__ x,
                                            const float* __restrict__ g,
                                            const float* __restrict__ b,
                                            __bf16* __restrict__ out, int N)
{
    int wid = blockIdx.x * 4 + (threadIdx.x >> 6);
    if (wid >= N) return;
    int lane = threadIdx.x & 63;
    const float4* row = (const float4*)(x + (size_t)wid * DMODEL);
    float v[12];
    float s = 0.f, sq = 0.f;
#pragma unroll
    for (int j = 0; j < 3; ++j) {
        float4 u = row[lane + 64 * j];
        float f0 = u.x, f1 = u.y, f2 = u.z, f3 = u.w;
        v[j*4+0] = f0; v[j*4+1] = f1; v[j*4+2] = f2; v[j*4+3] = f3;
        s += f0 + f1 + f2 + f3;
        sq += f0*f0 + f1*f1 + f2*f2 + f3*f3;
    }
#pragma unroll
    for (int o = 32; o >= 1; o >>= 1) { s += __shfl_xor(s, o); sq += __shfl_xor(sq, o); }
    float mu = s * (1.f / DMODEL);
    float var = sq * (1.f / DMODEL) - mu * mu;
    float rstd = rsqrtf(var + 1e-5f);
    bf16x4* orow = (bf16x4*)(out + (size_t)wid * DMODEL);
    const float4* gg = (const float4*)g;
    const float4* bb = (const float4*)b;
#pragma unroll
    for (int j = 0; j < 3; ++j) {
        float4 gu = gg[lane + 64*j], bu = bb[lane + 64*j];
        bf16x4 o4;
        o4[0] = (__bf16)((v[j*4+0] - mu) * rstd * gu.x + bu.x);
        o4[1] = (__bf16)((v[j*4+1] - mu) * rstd * gu.y + bu.y);
        o4[2] = (__bf16)((v[j*4+2] - mu) * rstd * gu.z + bu.z);
        o4[3] = (__bf16)((v[j*4+3] - mu) * rstd * gu.w + bu.w);
        orow[lane + 64*j] = o4;
    }
}

// x1 (f32, in-place) += st (bf16);  xn2 (bf16) = LN(x1)
__global__ __launch_bounds__(256) void addln_k(float* __restrict__ x1,
                                               const __bf16* __restrict__ st,
                                               const float* __restrict__ g,
                                               const float* __restrict__ b,
                                               __bf16* __restrict__ xn2, int N)
{
    int wid = blockIdx.x * 4 + (threadIdx.x >> 6);
    if (wid >= N) return;
    int lane = threadIdx.x & 63;
    float4* r1 = (float4*)(x1 + (size_t)wid * DMODEL);
    const bf16x4* r2 = (const bf16x4*)(st + (size_t)wid * DMODEL);
    float v[12];
    float s = 0.f, sq = 0.f;
#pragma unroll
    for (int j = 0; j < 3; ++j) {
        float4 u1 = r1[lane + 64*j];
        bf16x4 u2 = r2[lane + 64*j];
        float f0 = u1.x + b2f(u2[0]), f1 = u1.y + b2f(u2[1]);
        float f2 = u1.z + b2f(u2[2]), f3 = u1.w + b2f(u2[3]);
        v[j*4+0] = f0; v[j*4+1] = f1; v[j*4+2] = f2; v[j*4+3] = f3;
        s += f0 + f1 + f2 + f3;
        sq += f0*f0 + f1*f1 + f2*f2 + f3*f3;
        float4 o; o.x = f0; o.y = f1; o.z = f2; o.w = f3;
        r1[lane + 64*j] = o;
    }
#pragma unroll
    for (int o = 32; o >= 1; o >>= 1) { s += __shfl_xor(s, o); sq += __shfl_xor(sq, o); }
    float mu = s * (1.f / DMODEL);
    float var = sq * (1.f / DMODEL) - mu * mu;
    float rstd = rsqrtf(var + 1e-5f);
    bf16x4* on = (bf16x4*)(xn2 + (size_t)wid * DMODEL);
    const float4* gg = (const float4*)g;
    const float4* bb = (const float4*)b;
#pragma unroll
    for (int j = 0; j < 3; ++j) {
        float4 gu = gg[lane + 64*j], bu = bb[lane + 64*j];
        bf16x4 o4;
        o4[0] = (__bf16)((v[j*4+0] - mu) * rstd * gu.x + bu.x);
        o4[1] = (__bf16)((v[j*4+1] - mu) * rstd * gu.y + bu.y);
        o4[2] = (__bf16)((v[j*4+2] - mu) * rstd * gu.z + bu.z);
        o4[3] = (__bf16)((v[j*4+3] - mu) * rstd * gu.w + bu.w);
        on[lane + 64*j] = o4;
    }
}

// ---------------------------------------------------------------- GEMM (128x128): r9-verified kernel for M=768 GEMMs
// 8 waves (2x4), per-wave 64x32. T2 swizzle, single __syncthreads, XCD swizzle.
// EPI: 0 bf16 v+bias | 1 f32 v+bias+res_f32 | 2 bf16 gelu | 3 bf16 res+0.1v
template <int EPI>
__global__ __launch_bounds__(512) void gemm_k(const __bf16* __restrict__ A,
                                              const __bf16* __restrict__ W,
                                              const float* __restrict__ bias,
                                              const void* __restrict__ resv,
                                              void* __restrict__ outv,
                                              int Nv, int K)
{
    __shared__ __align__(16) __bf16 Al[2][128 * 64];
    __shared__ __align__(16) __bf16 Bl[2][128 * 64];
    const int tid = threadIdx.x;
    const int lane = tid & 63;
    const int wv = tid >> 6;
    const int wr = wv >> 2, wc = wv & 3;

    const int ncol = gridDim.x;
    const int nwg = ncol * gridDim.y;
    const int orig = blockIdx.x + ncol * blockIdx.y;
    const int q8 = nwg >> 3, r8 = nwg & 7;
    const int xcd = orig & 7, off8 = orig >> 3;
    const int wgid = (xcd < r8 ? xcd * (q8 + 1) : r8 * (q8 + 1) + (xcd - r8) * q8) + off8;
    const int bcol = (wgid % ncol) * 128;
    const int brow = (wgid / ncol) * 128;

    const int M = ncol * 128;
    const int srow = tid >> 3;
    const int scol = (tid & 7) * 8;
    const int sg = (((tid & 7) ^ (srow & 7)) << 3);
    const int lq = lane >> 4, lr = lane & 15;
    const int gsw = lr & 7;

    const __bf16* Arow[2];
    const __bf16* Wrow[2];
#pragma unroll
    for (int it = 0; it < 2; ++it) {
        int row = it * 64 + srow;
        int ar = brow + row; ar = ar < Nv ? ar : (Nv - 1);
        Arow[it] = A + (size_t)ar * K + sg;
        Wrow[it] = W + (size_t)(bcol + row) * K + sg;
    }

    f32x4 acc[4][2];
#pragma unroll
    for (int m = 0; m < 4; ++m)
#pragma unroll
        for (int n = 0; n < 2; ++n)
#pragma unroll
            for (int i = 0; i < 4; ++i) acc[m][n][i] = 0.f;

    const int nk = K >> 6;
#pragma unroll
    for (int it = 0; it < 2; ++it) {
        int row = it * 64 + srow;
        gload16(Arow[it], &Al[0][row * 64 + scol]);
        gload16(Wrow[it], &Bl[0][row * 64 + scol]);
    }
    __syncthreads();

    for (int t = 0; t < nk; ++t) {
        const int cur = t & 1;
        if (t + 1 < nk) {
            const int koff = (t + 1) << 6;
#pragma unroll
            for (int it = 0; it < 2; ++it) {
                int row = it * 64 + srow;
                gload16(Arow[it] + koff, &Al[cur ^ 1][row * 64 + scol]);
                gload16(Wrow[it] + koff, &Bl[cur ^ 1][row * 64 + scol]);
            }
        }
#pragma unroll
        for (int kk = 0; kk < 2; ++kk) {
            bf16x8 af[4], bfr[2];
            const int cg = ((kk * 4 + lq) ^ gsw) << 3;
#pragma unroll
            for (int m = 0; m < 4; ++m)
                af[m] = *(const bf16x8*)&Al[cur][(wr * 64 + m * 16 + lr) * 64 + cg];
#pragma unroll
            for (int n = 0; n < 2; ++n)
                bfr[n] = *(const bf16x8*)&Bl[cur][(wc * 32 + n * 16 + lr) * 64 + cg];
#pragma unroll
            for (int m = 0; m < 4; ++m)
#pragma unroll
                for (int n = 0; n < 2; ++n)
                    acc[m][n] = __builtin_amdgcn_mfma_f32_16x16x32_bf16(af[m], bfr[n], acc[m][n], 0, 0, 0);
        }
        __syncthreads();
    }

#pragma unroll
    for (int m = 0; m < 4; ++m) {
        int row0 = brow + wr * 64 + m * 16 + lq * 4;
#pragma unroll
        for (int n = 0; n < 2; ++n) {
            int col = bcol + wc * 32 + n * 16 + lr;
            float bv = bias[col];
#pragma unroll
            for (int i = 0; i < 4; ++i) {
                int row = row0 + i;
                if (row < Nv) {
                    float v = acc[m][n][i] + bv;
                    size_t off = (size_t)row * M + col;
                    if constexpr (EPI == 0) {
                        ((__bf16*)outv)[off] = (__bf16)v;
                    } else if constexpr (EPI == 1) {
                        ((float*)outv)[off] = v + ((const float*)resv)[off];
                    } else if constexpr (EPI == 2) {
                        ((__bf16*)outv)[off] = (__bf16)gelu_f(v);
                    } else {
                        ((__bf16*)outv)[off] = (__bf16)(b2f(((const __bf16*)resv)[off]) + 0.1f * v);
                    }
                }
            }
        }
    }
}

// ---------------------------------------------------------------- GEMM2 (256x128): for wide-M GEMMs (QKV, FFN1)
// BM=256, BN=128, BK=64, 8 waves (4M x 2N), per-wave 64x64 (acc[4][4]):
// 8 ds_read_b128 per kk feed 16 MFMA (0.5 reads/MFMA at full 8-wave TLP);
// one barrier per 256x128x64 of work. Same T2 swizzle / sync / XCD swizzle.
template <int EPI>
__global__ __launch_bounds__(512) void gemm2_k(const __bf16* __restrict__ A,
                                               const __bf16* __restrict__ W,
                                               const float* __restrict__ bias,
                                               const void* __restrict__ resv,
                                               void* __restrict__ outv,
                                               int Nv, int K)
{
    __shared__ __align__(16) __bf16 Al[2][256 * 64];   // 64 KB
    __shared__ __align__(16) __bf16 Bl[2][128 * 64];   // 32 KB
    const int tid = threadIdx.x;
    const int lane = tid & 63;
    const int wv = tid >> 6;              // 0..7
    const int wr = wv >> 1, wc = wv & 1;  // 4M x 2N wave grid, 64x64 each

    const int ncol = gridDim.x;
    const int nwg = ncol * gridDim.y;
    const int orig = blockIdx.x + ncol * blockIdx.y;
    const int q8 = nwg >> 3, r8 = nwg & 7;
    const int xcd = orig & 7, off8 = orig >> 3;
    const int wgid = (xcd < r8 ? xcd * (q8 + 1) : r8 * (q8 + 1) + (xcd - r8) * q8) + off8;
    const int bcol = (wgid % ncol) * 128;
    const int brow = (wgid / ncol) * 256;

    const int M = ncol * 128;             // ldc
    const int srow = tid >> 3;            // 0..63
    const int scol = (tid & 7) * 8;
    const int sg = (((tid & 7) ^ (srow & 7)) << 3);
    const int lq = lane >> 4, lr = lane & 15;
    const int gsw = lr & 7;

    // A: 4 staging iters x 64 rows (256 total); B: 2 iters x 64 rows (128).
    // (it*64 + srow) & 7 == srow & 7 -> one sg serves all iters.
    const __bf16* Arow[4];
    const __bf16* Wrow[2];
#pragma unroll
    for (int it = 0; it < 4; ++it) {
        int row = it * 64 + srow;
        int ar = brow + row; ar = ar < Nv ? ar : (Nv - 1);
        Arow[it] = A + (size_t)ar * K + sg;
    }
#pragma unroll
    for (int it = 0; it < 2; ++it) {
        int row = it * 64 + srow;
        Wrow[it] = W + (size_t)(bcol + row) * K + sg;
    }

    f32x4 acc[4][4];
#pragma unroll
    for (int m = 0; m < 4; ++m)
#pragma unroll
        for (int n = 0; n < 4; ++n)
#pragma unroll
            for (int i = 0; i < 4; ++i) acc[m][n][i] = 0.f;

    const int nk = K >> 6;
#pragma unroll
    for (int it = 0; it < 4; ++it)
        gload16(Arow[it], &Al[0][(it * 64 + srow) * 64 + scol]);
#pragma unroll
    for (int it = 0; it < 2; ++it)
        gload16(Wrow[it], &Bl[0][(it * 64 + srow) * 64 + scol]);
    __syncthreads();

    for (int t = 0; t < nk; ++t) {
        const int cur = t & 1;
        if (t + 1 < nk) {
            const int koff = (t + 1) << 6;
#pragma unroll
            for (int it = 0; it < 4; ++it)
                gload16(Arow[it] + koff, &Al[cur ^ 1][(it * 64 + srow) * 64 + scol]);
#pragma unroll
            for (int it = 0; it < 2; ++it)
                gload16(Wrow[it] + koff, &Bl[cur ^ 1][(it * 64 + srow) * 64 + scol]);
        }
#pragma unroll
        for (int kk = 0; kk < 2; ++kk) {
            bf16x8 af[4], bfr[4];
            const int cg = ((kk * 4 + lq) ^ gsw) << 3;
#pragma unroll
            for (int m = 0; m < 4; ++m)
                af[m] = *(const bf16x8*)&Al[cur][(wr * 64 + m * 16 + lr) * 64 + cg];
#pragma unroll
            for (int n = 0; n < 4; ++n)
                bfr[n] = *(const bf16x8*)&Bl[cur][(wc * 64 + n * 16 + lr) * 64 + cg];
#pragma unroll
            for (int m = 0; m < 4; ++m)
#pragma unroll
                for (int n = 0; n < 4; ++n)
                    acc[m][n] = __builtin_amdgcn_mfma_f32_16x16x32_bf16(af[m], bfr[n], acc[m][n], 0, 0, 0);
        }
        __syncthreads();
    }

#pragma unroll
    for (int m = 0; m < 4; ++m) {
        int row0 = brow + wr * 64 + m * 16 + lq * 4;
#pragma unroll
        for (int n = 0; n < 4; ++n) {
            int col = bcol + wc * 64 + n * 16 + lr;
            float bv = bias[col];
#pragma unroll
            for (int i = 0; i < 4; ++i) {
                int row = row0 + i;
                if (row < Nv) {
                    float v = acc[m][n][i] + bv;
                    size_t off = (size_t)row * M + col;
                    if constexpr (EPI == 0) {
                        ((__bf16*)outv)[off] = (__bf16)v;
                    } else if constexpr (EPI == 1) {
                        ((float*)outv)[off] = v + ((const float*)resv)[off];
                    } else if constexpr (EPI == 2) {
                        ((__bf16*)outv)[off] = (__bf16)gelu_f(v);
                    } else {
                        ((__bf16*)outv)[off] = (__bf16)(b2f(((const __bf16*)resv)[off]) + 0.1f * v);
                    }
                }
            }
        }
    }
}

// ---------------------------------------------------------------- attention: TWO blocks per (b,h) (q-tile split)
__global__ __launch_bounds__(256) void attn_k(const __bf16* __restrict__ qkv,
                                              __bf16* __restrict__ attn_out)
{
    constexpr int S = SEQ, LDP = 232, QKVW = 2304;
    __shared__ __align__(16) __bf16 Vt[64 * LDP];       // [d][j]
    __shared__ __align__(16) __bf16 P[4][16 * LDP];     // per wave [q][j]
    const int bh = blockIdx.x >> 1;
    const int half = blockIdx.x & 1;
    const int b = bh / 12, h = bh % 12;
    const size_t base = (size_t)b * S * QKVW;
    const int tid = threadIdx.x, lane = tid & 63, wv = tid >> 6;
    const int lq = lane >> 4, lr = lane & 15;

    // stage V transposed, zero-pad j in [197,224)
    for (int idx = tid; idx < 224 * 8; idx += 256) {
        int j = idx >> 3, d0 = (idx & 7) * 8;
        bf16x8 v8;
        if (j < S) v8 = *(const bf16x8*)(qkv + base + (size_t)j * QKVW + 1536 + h * 64 + d0);
        else {
#pragma unroll
            for (int e = 0; e < 8; ++e) v8[e] = (__bf16)0.f;
        }
#pragma unroll
        for (int e = 0; e < 8; ++e) Vt[(d0 + e) * LDP + j] = v8[e];
    }
    __syncthreads();

    for (int qt = wv + half * 4; qt < 13; qt += 8) {
        int q0 = qt * 16;
        int qrow = q0 + lr; qrow = qrow < S ? qrow : (S - 1);
        bf16x8 aq[2];
#pragma unroll
        for (int kk = 0; kk < 2; ++kk)
            aq[kk] = *(const bf16x8*)(qkv + base + (size_t)qrow * QKVW + h * 64 + kk * 32 + lq * 8);

        f32x4 sc[14];
#pragma unroll
        for (int jf = 0; jf < 14; ++jf) {
#pragma unroll
            for (int i = 0; i < 4; ++i) sc[jf][i] = 0.f;
            int j = jf * 16 + lr; int jc = j < S ? j : (S - 1);
#pragma unroll
            for (int kk = 0; kk < 2; ++kk) {
                bf16x8 bk = *(const bf16x8*)(qkv + base + (size_t)jc * QKVW + 768 + h * 64 + kk * 32 + lq * 8);
                sc[jf] = __builtin_amdgcn_mfma_f32_16x16x32_bf16(aq[kk], bk, sc[jf], 0, 0, 0);
            }
        }
        bool colv[14];
#pragma unroll
        for (int jf = 0; jf < 14; ++jf) colv[jf] = (jf * 16 + lr) < S;
#pragma unroll
        for (int i = 0; i < 4; ++i) {
            float mx = -1.0e30f;
#pragma unroll
            for (int jf = 0; jf < 14; ++jf) {
                float sv = colv[jf] ? sc[jf][i] : -1.0e30f;
                sc[jf][i] = sv;
                mx = fmaxf(mx, sv);
            }
#pragma unroll
            for (int o = 8; o >= 1; o >>= 1) mx = fmaxf(mx, __shfl_xor(mx, o));
            float sm = 0.f;
#pragma unroll
            for (int jf = 0; jf < 14; ++jf) {
                float p = expf((sc[jf][i] - mx) * 0.125f);
                sc[jf][i] = p; sm += p;
            }
#pragma unroll
            for (int o = 8; o >= 1; o >>= 1) sm += __shfl_xor(sm, o);
            float inv = 1.f / sm;
#pragma unroll
            for (int jf = 0; jf < 14; ++jf)
                P[wv][(lq * 4 + i) * LDP + jf * 16 + lr] = (__bf16)(sc[jf][i] * inv);
        }
        f32x4 o4[4];
#pragma unroll
        for (int df = 0; df < 4; ++df)
#pragma unroll
            for (int i = 0; i < 4; ++i) o4[df][i] = 0.f;
#pragma unroll
        for (int ks = 0; ks < 7; ++ks) {
            bf16x8 pa = *(const bf16x8*)&P[wv][lr * LDP + ks * 32 + lq * 8];
#pragma unroll
            for (int df = 0; df < 4; ++df) {
                bf16x8 vb = *(const bf16x8*)&Vt[(df * 16 + lr) * LDP + ks * 32 + lq * 8];
                o4[df] = __builtin_amdgcn_mfma_f32_16x16x32_bf16(pa, vb, o4[df], 0, 0, 0);
            }
        }
#pragma unroll
        for (int df = 0; df < 4; ++df)
#pragma unroll
            for (int i = 0; i < 4; ++i) {
                int qr = q0 + lq * 4 + i;
                if (qr < S)
                    attn_out[((size_t)b * S + qr) * DMODEL + h * 64 + df * 16 + lr] = (__bf16)o4[df][i];
            }
    }
}

// ---------------------------------------------------------------- launch
extern "C" void kernel_launch(void* const* d_in, const int* in_sizes, int n_in,
                              void* d_out, int out_size, void* d_ws, size_t ws_size,
                              hipStream_t stream) {
    const float* x      = (const float*)d_in[0];
    const float* in_w   = (const float*)d_in[1];
    const float* in_b   = (const float*)d_in[2];
    const float* out_w  = (const float*)d_in[3];
    const float* out_b  = (const float*)d_in[4];
    const float* lnA_g  = (const float*)d_in[5];
    const float* lnA_b  = (const float*)d_in[6];
    const float* ln1_g  = (const float*)d_in[7];
    const float* ln1_b  = (const float*)d_in[8];
    const float* ln2_g  = (const float*)d_in[9];
    const float* ln2_b  = (const float*)d_in[10];
    const float* inl_w1 = (const float*)d_in[11];
    const float* inl_b1 = (const float*)d_in[12];
    const float* inl_w2 = (const float*)d_in[13];
    const float* inl_b2 = (const float*)d_in[14];
    const float* ffn_w1 = (const float*)d_in[15];
    const float* ffn_b1 = (const float*)d_in[16];
    const float* ffn_w2 = (const float*)d_in[17];
    const float* ffn_b2 = (const float*)d_in[18];

    const int N = NTOK;
    const size_t sz_inw = (size_t)2304 * 768, sz_outw = (size_t)768 * 768;
    const size_t sz_i1 = (size_t)768 * 768, sz_i2 = (size_t)768 * 768;
    const size_t sz_f1 = (size_t)3072 * 768, sz_f2 = (size_t)768 * 3072;
    const size_t wtot = sz_inw + sz_outw + sz_i1 + sz_i2 + sz_f1 + sz_f2;

    const size_t bA = (size_t)N * 3072 * 2;
    const size_t bB = (size_t)N * 768 * 2;
    const size_t bS = (size_t)N * 768 * 2;
    const size_t bX = (size_t)N * 768 * 4;
    const size_t need = wtot * 2 + bA + bB + bS + bX;
    if (ws_size < need) {
        fprintf(stderr, "kernel_launch: ws_size %zu < required %zu\n", ws_size, need);
        return;
    }
    char* ws = (char*)d_ws;
    __bf16* w_in  = (__bf16*)ws;
    __bf16* w_out = w_in + sz_inw;
    __bf16* w_i1  = w_out + sz_outw;
    __bf16* w_i2  = w_i1 + sz_i1;
    __bf16* w_f1  = w_i2 + sz_i2;
    __bf16* w_f2  = w_f1 + sz_f1;
    char* p = ws + wtot * 2;
    __bf16* bufA = (__bf16*)p;            p += bA;
    __bf16* bufB = (__bf16*)p;            p += bB;
    __bf16* st   = (__bf16*)p;            p += bS;
    float*  x1   = (float*)p;

    dim3 blk(256), gblk(512);
    const int lnGrid = (N + 3) / 4;
    const int nrow = 99;   // ceil(12608/128)
    const int nrow2 = 50;  // ceil(12608/256)

    CvtArgs ca;
    ca.src[0] = in_w;   ca.dst[0] = w_in;  ca.n4[0] = (int)(sz_inw / 4);
    ca.src[1] = out_w;  ca.dst[1] = w_out; ca.n4[1] = (int)(sz_outw / 4);
    ca.src[2] = inl_w1; ca.dst[2] = w_i1;  ca.n4[2] = (int)(sz_i1 / 4);
    ca.src[3] = inl_w2; ca.dst[3] = w_i2;  ca.n4[3] = (int)(sz_i2 / 4);
    ca.src[4] = ffn_w1; ca.dst[4] = w_f1;  ca.n4[4] = (int)(sz_f1 / 4);
    ca.src[5] = ffn_w2; ca.dst[5] = w_f2;  ca.n4[5] = (int)(sz_f2 / 4);
    cvt_all_k<<<dim3(1024), blk, 0, stream>>>(ca);

    // 1. xn = LN(x)
    ln_k<<<dim3(lnGrid), blk, 0, stream>>>(x, lnA_g, lnA_b, bufB, N);
    // 2. qkv = xn @ in_w^T + in_b          (256x128 tile kernel)
    gemm2_k<0><<<dim3(18, nrow2), gblk, 0, stream>>>(bufB, w_in, in_b, nullptr, bufA, N, 768);
    // 3. attn (2 blocks per head)
    attn_k<<<dim3(1536), blk, 0, stream>>>(bufA, bufB);
    // 4. x1 = x + attn_out @ out_w^T + out_b
    gemm_k<1><<<dim3(6, nrow), gblk, 0, stream>>>(bufB, w_out, out_b, x, x1, N, 768);
    // 5. st = LN(x1)
    ln_k<<<dim3(lnGrid), blk, 0, stream>>>(x1, ln1_g, ln1_b, st, N);
    // 6. INL loop
    for (int it = 0; it < 5; ++it) {
        gemm_k<2><<<dim3(6, nrow), gblk, 0, stream>>>(st, w_i1, inl_b1, nullptr, bufA, N, 768);
        gemm_k<3><<<dim3(6, nrow), gblk, 0, stream>>>(bufA, w_i2, inl_b2, st, st, N, 768);
    }
    // 7. x1 += st; xn2 = LN(x1)
    addln_k<<<dim3(lnGrid), blk, 0, stream>>>(x1, st, ln2_g, ln2_b, bufB, N);
    // 8. h2 = gelu(xn2 @ ffn_w1^T + b1)    (256x128 tile kernel)
    gemm2_k<2><<<dim3(24, nrow2), gblk, 0, stream>>>(bufB, w_f1, ffn_b1, nullptr, bufA, N, 768);
    // 9. out = x1 + h2 @ ffn_w2^T + b2
    gemm_k<1><<<dim3(6, nrow), gblk, 0, stream>>>(bufA, w_f2, ffn_b2, x1, (float*)d_out, N, 3072);
}

// Round 11
// 835.609 us; speedup vs baseline: 1.0364x; 1.0364x over previous
//
#include <hip/hip_runtime.h>
#include <hip/hip_bf16.h>
#include <cstdio>

// ---------------------------------------------------------------- types
typedef __bf16 bf16x4 __attribute__((ext_vector_type(4)));
typedef __bf16 bf16x8 __attribute__((ext_vector_type(8)));
typedef float  f32x4  __attribute__((ext_vector_type(4)));

#define NTOK 12608   // B*S = 64*197
#define DMODEL 768
#define SEQ 197

__device__ __forceinline__ float b2f(__bf16 v) { return (float)v; }

// fast GELU (tanh form, one v_exp_f32; |err| vs exact erf-GELU < ~3e-4)
__device__ __forceinline__ float gelu_f(float x) {
    float y = 1.5957691216f * (x + 0.044715f * x * x * x);
    float e = __expf(y);
    float t = 1.f - 2.f / (e + 1.f);
    return 0.5f * x * (1.f + t);
}

__device__ __forceinline__ void gload16(const void* src, void* dst) {
    __builtin_amdgcn_global_load_lds(
        (const __attribute__((address_space(1))) void*)src,
        (__attribute__((address_space(3))) void*)dst,
        16, 0, 0);
}

// ---------------------------------------------------------------- f32 -> bf16 convert (all 6 weights, one launch)
struct CvtArgs {
    const float* src[6];
    __bf16* dst[6];
    int n4[6];
};
__global__ __launch_bounds__(256) void cvt_all_k(CvtArgs a)
{
#pragma unroll
    for (int t = 0; t < 6; ++t) {
        const float4* in = (const float4*)a.src[t];
        bf16x4* out = (bf16x4*)a.dst[t];
        const int n4 = a.n4[t];
        for (int i = blockIdx.x * 256 + threadIdx.x; i < n4; i += gridDim.x * 256) {
            float4 v = in[i];
            bf16x4 o;
            o[0] = (__bf16)v.x; o[1] = (__bf16)v.y; o[2] = (__bf16)v.z; o[3] = (__bf16)v.w;
            out[i] = o;
        }
    }
}

// ---------------------------------------------------------------- LayerNorm (f32 in -> bf16 out), 1 wave/row
__global__ __launch_bounds__(256) void ln_k(const float* __restrict__ x,
                                            const float* __restrict__ g,
                                            const float* __restrict__ b,
                                            __bf16* __restrict__ out, int N)
{
    int wid = blockIdx.x * 4 + (threadIdx.x >> 6);
    if (wid >= N) return;
    int lane = threadIdx.x & 63;
    const float4* row = (const float4*)(x + (size_t)wid * DMODEL);
    float v[12];
    float s = 0.f, sq = 0.f;
#pragma unroll
    for (int j = 0; j < 3; ++j) {
        float4 u = row[lane + 64 * j];
        float f0 = u.x, f1 = u.y, f2 = u.z, f3 = u.w;
        v[j*4+0] = f0; v[j*4+1] = f1; v[j*4+2] = f2; v[j*4+3] = f3;
        s += f0 + f1 + f2 + f3;
        sq += f0*f0 + f1*f1 + f2*f2 + f3*f3;
    }
#pragma unroll
    for (int o = 32; o >= 1; o >>= 1) { s += __shfl_xor(s, o); sq += __shfl_xor(sq, o); }
    float mu = s * (1.f / DMODEL);
    float var = sq * (1.f / DMODEL) - mu * mu;
    float rstd = rsqrtf(var + 1e-5f);
    bf16x4* orow = (bf16x4*)(out + (size_t)wid * DMODEL);
    const float4* gg = (const float4*)g;
    const float4* bb = (const float4*)b;
#pragma unroll
    for (int j = 0; j < 3; ++j) {
        float4 gu = gg[lane + 64*j], bu = bb[lane + 64*j];
        bf16x4 o4;
        o4[0] = (__bf16)((v[j*4+0] - mu) * rstd * gu.x + bu.x);
        o4[1] = (__bf16)((v[j*4+1] - mu) * rstd * gu.y + bu.y);
        o4[2] = (__bf16)((v[j*4+2] - mu) * rstd * gu.z + bu.z);
        o4[3] = (__bf16)((v[j*4+3] - mu) * rstd * gu.w + bu.w);
        orow[lane + 64*j] = o4;
    }
}

// x1 (f32, in-place) += st (bf16);  xn2 (bf16) = LN(x1)
__global__ __launch_bounds__(256) void addln_k(float* __restrict__ x1,
                                               const __bf16* __restrict__ st,
                                               const float* __restrict__ g,
                                               const float* __restrict__ b,
                                               __bf16* __restrict__ xn2, int N)
{
    int wid = blockIdx.x * 4 + (threadIdx.x >> 6);
    if (wid >= N) return;
    int lane = threadIdx.x & 63;
    float4* r1 = (float4*)(x1 + (size_t)wid * DMODEL);
    const bf16x4* r2 = (const bf16x4*)(st + (size_t)wid * DMODEL);
    float v[12];
    float s = 0.f, sq = 0.f;
#pragma unroll
    for (int j = 0; j < 3; ++j) {
        float4 u1 = r1[lane + 64*j];
        bf16x4 u2 = r2[lane + 64*j];
        float f0 = u1.x + b2f(u2[0]), f1 = u1.y + b2f(u2[1]);
        float f2 = u1.z + b2f(u2[2]), f3 = u1.w + b2f(u2[3]);
        v[j*4+0] = f0; v[j*4+1] = f1; v[j*4+2] = f2; v[j*4+3] = f3;
        s += f0 + f1 + f2 + f3;
        sq += f0*f0 + f1*f1 + f2*f2 + f3*f3;
        float4 o; o.x = f0; o.y = f1; o.z = f2; o.w = f3;
        r1[lane + 64*j] = o;
    }
#pragma unroll
    for (int o = 32; o >= 1; o >>= 1) { s += __shfl_xor(s, o); sq += __shfl_xor(sq, o); }
    float mu = s * (1.f / DMODEL);
    float var = sq * (1.f / DMODEL) - mu * mu;
    float rstd = rsqrtf(var + 1e-5f);
    bf16x4* on = (bf16x4*)(xn2 + (size_t)wid * DMODEL);
    const float4* gg = (const float4*)g;
    const float4* bb = (const float4*)b;
#pragma unroll
    for (int j = 0; j < 3; ++j) {
        float4 gu = gg[lane + 64*j], bu = bb[lane + 64*j];
        bf16x4 o4;
        o4[0] = (__bf16)((v[j*4+0] - mu) * rstd * gu.x + bu.x);
        o4[1] = (__bf16)((v[j*4+1] - mu) * rstd * gu.y + bu.y);
        o4[2] = (__bf16)((v[j*4+2] - mu) * rstd * gu.z + bu.z);
        o4[3] = (__bf16)((v[j*4+3] - mu) * rstd * gu.w + bu.w);
        on[lane + 64*j] = o4;
    }
}

// ---------------------------------------------------------------- GEMM (128x128): r9-verified kernel, used for ALL GEMMs.
// 8 waves (2x4), per-wave 64x32, 64 KB LDS (2 blocks/CU -- the resident-block
// overlap is what hides the per-step barrier drain; r8/r10 proved bigger
// per-block tiles at 1 block/CU lose more than they gain).
// T2 swizzle (conflicts=0): linear LDS dest, source col group ^= row&7,
// read group ^= lr&7. Sync: stage(next) -> MFMA(cur) -> __syncthreads.
// XCD-chunked bijective block swizzle (m204).
// EPI: 0 bf16 v+bias | 1 f32 v+bias+res_f32 | 2 bf16 gelu | 3 bf16 res+0.1v
template <int EPI>
__global__ __launch_bounds__(512) void gemm_k(const __bf16* __restrict__ A,
                                              const __bf16* __restrict__ W,
                                              const float* __restrict__ bias,
                                              const void* __restrict__ resv,
                                              void* __restrict__ outv,
                                              int Nv, int K)
{
    __shared__ __align__(16) __bf16 Al[2][128 * 64];
    __shared__ __align__(16) __bf16 Bl[2][128 * 64];
    const int tid = threadIdx.x;
    const int lane = tid & 63;
    const int wv = tid >> 6;
    const int wr = wv >> 2, wc = wv & 3;

    const int ncol = gridDim.x;
    const int nwg = ncol * gridDim.y;
    const int orig = blockIdx.x + ncol * blockIdx.y;
    const int q8 = nwg >> 3, r8 = nwg & 7;
    const int xcd = orig & 7, off8 = orig >> 3;
    const int wgid = (xcd < r8 ? xcd * (q8 + 1) : r8 * (q8 + 1) + (xcd - r8) * q8) + off8;
    const int bcol = (wgid % ncol) * 128;
    const int brow = (wgid / ncol) * 128;

    const int M = ncol * 128;
    const int srow = tid >> 3;
    const int scol = (tid & 7) * 8;
    const int sg = (((tid & 7) ^ (srow & 7)) << 3);
    const int lq = lane >> 4, lr = lane & 15;
    const int gsw = lr & 7;

    const __bf16* Arow[2];
    const __bf16* Wrow[2];
#pragma unroll
    for (int it = 0; it < 2; ++it) {
        int row = it * 64 + srow;
        int ar = brow + row; ar = ar < Nv ? ar : (Nv - 1);
        Arow[it] = A + (size_t)ar * K + sg;
        Wrow[it] = W + (size_t)(bcol + row) * K + sg;
    }

    f32x4 acc[4][2];
#pragma unroll
    for (int m = 0; m < 4; ++m)
#pragma unroll
        for (int n = 0; n < 2; ++n)
#pragma unroll
            for (int i = 0; i < 4; ++i) acc[m][n][i] = 0.f;

    const int nk = K >> 6;
#pragma unroll
    for (int it = 0; it < 2; ++it) {
        int row = it * 64 + srow;
        gload16(Arow[it], &Al[0][row * 64 + scol]);
        gload16(Wrow[it], &Bl[0][row * 64 + scol]);
    }
    __syncthreads();

    for (int t = 0; t < nk; ++t) {
        const int cur = t & 1;
        if (t + 1 < nk) {
            const int koff = (t + 1) << 6;
#pragma unroll
            for (int it = 0; it < 2; ++it) {
                int row = it * 64 + srow;
                gload16(Arow[it] + koff, &Al[cur ^ 1][row * 64 + scol]);
                gload16(Wrow[it] + koff, &Bl[cur ^ 1][row * 64 + scol]);
            }
        }
#pragma unroll
        for (int kk = 0; kk < 2; ++kk) {
            bf16x8 af[4], bfr[2];
            const int cg = ((kk * 4 + lq) ^ gsw) << 3;
#pragma unroll
            for (int m = 0; m < 4; ++m)
                af[m] = *(const bf16x8*)&Al[cur][(wr * 64 + m * 16 + lr) * 64 + cg];
#pragma unroll
            for (int n = 0; n < 2; ++n)
                bfr[n] = *(const bf16x8*)&Bl[cur][(wc * 32 + n * 16 + lr) * 64 + cg];
#pragma unroll
            for (int m = 0; m < 4; ++m)
#pragma unroll
                for (int n = 0; n < 2; ++n)
                    acc[m][n] = __builtin_amdgcn_mfma_f32_16x16x32_bf16(af[m], bfr[n], acc[m][n], 0, 0, 0);
        }
        __syncthreads();
    }

#pragma unroll
    for (int m = 0; m < 4; ++m) {
        int row0 = brow + wr * 64 + m * 16 + lq * 4;
#pragma unroll
        for (int n = 0; n < 2; ++n) {
            int col = bcol + wc * 32 + n * 16 + lr;
            float bv = bias[col];
#pragma unroll
            for (int i = 0; i < 4; ++i) {
                int row = row0 + i;
                if (row < Nv) {
                    float v = acc[m][n][i] + bv;
                    size_t off = (size_t)row * M + col;
                    if constexpr (EPI == 0) {
                        ((__bf16*)outv)[off] = (__bf16)v;
                    } else if constexpr (EPI == 1) {
                        ((float*)outv)[off] = v + ((const float*)resv)[off];
                    } else if constexpr (EPI == 2) {
                        ((__bf16*)outv)[off] = (__bf16)gelu_f(v);
                    } else {
                        ((__bf16*)outv)[off] = (__bf16)(b2f(((const __bf16*)resv)[off]) + 0.1f * v);
                    }
                }
            }
        }
    }
}

// ---------------------------------------------------------------- attention: TWO blocks per (b,h) (q-tile split, r10)
__global__ __launch_bounds__(256) void attn_k(const __bf16* __restrict__ qkv,
                                              __bf16* __restrict__ attn_out)
{
    constexpr int S = SEQ, LDP = 232, QKVW = 2304;
    __shared__ __align__(16) __bf16 Vt[64 * LDP];       // [d][j]
    __shared__ __align__(16) __bf16 P[4][16 * LDP];     // per wave [q][j]
    const int bh = blockIdx.x >> 1;
    const int half = blockIdx.x & 1;
    const int b = bh / 12, h = bh % 12;
    const size_t base = (size_t)b * S * QKVW;
    const int tid = threadIdx.x, lane = tid & 63, wv = tid >> 6;
    const int lq = lane >> 4, lr = lane & 15;

    for (int idx = tid; idx < 224 * 8; idx += 256) {
        int j = idx >> 3, d0 = (idx & 7) * 8;
        bf16x8 v8;
        if (j < S) v8 = *(const bf16x8*)(qkv + base + (size_t)j * QKVW + 1536 + h * 64 + d0);
        else {
#pragma unroll
            for (int e = 0; e < 8; ++e) v8[e] = (__bf16)0.f;
        }
#pragma unroll
        for (int e = 0; e < 8; ++e) Vt[(d0 + e) * LDP + j] = v8[e];
    }
    __syncthreads();

    for (int qt = wv + half * 4; qt < 13; qt += 8) {
        int q0 = qt * 16;
        int qrow = q0 + lr; qrow = qrow < S ? qrow : (S - 1);
        bf16x8 aq[2];
#pragma unroll
        for (int kk = 0; kk < 2; ++kk)
            aq[kk] = *(const bf16x8*)(qkv + base + (size_t)qrow * QKVW + h * 64 + kk * 32 + lq * 8);

        f32x4 sc[14];
#pragma unroll
        for (int jf = 0; jf < 14; ++jf) {
#pragma unroll
            for (int i = 0; i < 4; ++i) sc[jf][i] = 0.f;
            int j = jf * 16 + lr; int jc = j < S ? j : (S - 1);
#pragma unroll
            for (int kk = 0; kk < 2; ++kk) {
                bf16x8 bk = *(const bf16x8*)(qkv + base + (size_t)jc * QKVW + 768 + h * 64 + kk * 32 + lq * 8);
                sc[jf] = __builtin_amdgcn_mfma_f32_16x16x32_bf16(aq[kk], bk, sc[jf], 0, 0, 0);
            }
        }
        bool colv[14];
#pragma unroll
        for (int jf = 0; jf < 14; ++jf) colv[jf] = (jf * 16 + lr) < S;
#pragma unroll
        for (int i = 0; i < 4; ++i) {
            float mx = -1.0e30f;
#pragma unroll
            for (int jf = 0; jf < 14; ++jf) {
                float sv = colv[jf] ? sc[jf][i] : -1.0e30f;
                sc[jf][i] = sv;
                mx = fmaxf(mx, sv);
            }
#pragma unroll
            for (int o = 8; o >= 1; o >>= 1) mx = fmaxf(mx, __shfl_xor(mx, o));
            float sm = 0.f;
#pragma unroll
            for (int jf = 0; jf < 14; ++jf) {
                float p = expf((sc[jf][i] - mx) * 0.125f);
                sc[jf][i] = p; sm += p;
            }
#pragma unroll
            for (int o = 8; o >= 1; o >>= 1) sm += __shfl_xor(sm, o);
            float inv = 1.f / sm;
#pragma unroll
            for (int jf = 0; jf < 14; ++jf)
                P[wv][(lq * 4 + i) * LDP + jf * 16 + lr] = (__bf16)(sc[jf][i] * inv);
        }
        f32x4 o4[4];
#pragma unroll
        for (int df = 0; df < 4; ++df)
#pragma unroll
            for (int i = 0; i < 4; ++i) o4[df][i] = 0.f;
#pragma unroll
        for (int ks = 0; ks < 7; ++ks) {
            bf16x8 pa = *(const bf16x8*)&P[wv][lr * LDP + ks * 32 + lq * 8];
#pragma unroll
            for (int df = 0; df < 4; ++df) {
                bf16x8 vb = *(const bf16x8*)&Vt[(df * 16 + lr) * LDP + ks * 32 + lq * 8];
                o4[df] = __builtin_amdgcn_mfma_f32_16x16x32_bf16(pa, vb, o4[df], 0, 0, 0);
            }
        }
#pragma unroll
        for (int df = 0; df < 4; ++df)
#pragma unroll
            for (int i = 0; i < 4; ++i) {
                int qr = q0 + lq * 4 + i;
                if (qr < S)
                    attn_out[((size_t)b * S + qr) * DMODEL + h * 64 + df * 16 + lr] = (__bf16)o4[df][i];
            }
    }
}

// ---------------------------------------------------------------- launch
extern "C" void kernel_launch(void* const* d_in, const int* in_sizes, int n_in,
                              void* d_out, int out_size, void* d_ws, size_t ws_size,
                              hipStream_t stream) {
    const float* x      = (const float*)d_in[0];
    const float* in_w   = (const float*)d_in[1];
    const float* in_b   = (const float*)d_in[2];
    const float* out_w  = (const float*)d_in[3];
    const float* out_b  = (const float*)d_in[4];
    const float* lnA_g  = (const float*)d_in[5];
    const float* lnA_b  = (const float*)d_in[6];
    const float* ln1_g  = (const float*)d_in[7];
    const float* ln1_b  = (const float*)d_in[8];
    const float* ln2_g  = (const float*)d_in[9];
    const float* ln2_b  = (const float*)d_in[10];
    const float* inl_w1 = (const float*)d_in[11];
    const float* inl_b1 = (const float*)d_in[12];
    const float* inl_w2 = (const float*)d_in[13];
    const float* inl_b2 = (const float*)d_in[14];
    const float* ffn_w1 = (const float*)d_in[15];
    const float* ffn_b1 = (const float*)d_in[16];
    const float* ffn_w2 = (const float*)d_in[17];
    const float* ffn_b2 = (const float*)d_in[18];

    const int N = NTOK;
    const size_t sz_inw = (size_t)2304 * 768, sz_outw = (size_t)768 * 768;
    const size_t sz_i1 = (size_t)768 * 768, sz_i2 = (size_t)768 * 768;
    const size_t sz_f1 = (size_t)3072 * 768, sz_f2 = (size_t)768 * 3072;
    const size_t wtot = sz_inw + sz_outw + sz_i1 + sz_i2 + sz_f1 + sz_f2;

    const size_t bA = (size_t)N * 3072 * 2;
    const size_t bB = (size_t)N * 768 * 2;
    const size_t bS = (size_t)N * 768 * 2;
    const size_t bX = (size_t)N * 768 * 4;
    const size_t need = wtot * 2 + bA + bB + bS + bX;
    if (ws_size < need) {
        fprintf(stderr, "kernel_launch: ws_size %zu < required %zu\n", ws_size, need);
        return;
    }
    char* ws = (char*)d_ws;
    __bf16* w_in  = (__bf16*)ws;
    __bf16* w_out = w_in + sz_inw;
    __bf16* w_i1  = w_out + sz_outw;
    __bf16* w_i2  = w_i1 + sz_i1;
    __bf16* w_f1  = w_i2 + sz_i2;
    __bf16* w_f2  = w_f1 + sz_f1;
    char* p = ws + wtot * 2;
    __bf16* bufA = (__bf16*)p;            p += bA;
    __bf16* bufB = (__bf16*)p;            p += bB;
    __bf16* st   = (__bf16*)p;            p += bS;
    float*  x1   = (float*)p;

    dim3 blk(256), gblk(512);
    const int lnGrid = (N + 3) / 4;
    const int nrow = 99;   // ceil(12608/128)

    CvtArgs ca;
    ca.src[0] = in_w;   ca.dst[0] = w_in;  ca.n4[0] = (int)(sz_inw / 4);
    ca.src[1] = out_w;  ca.dst[1] = w_out; ca.n4[1] = (int)(sz_outw / 4);
    ca.src[2] = inl_w1; ca.dst[2] = w_i1;  ca.n4[2] = (int)(sz_i1 / 4);
    ca.src[3] = inl_w2; ca.dst[3] = w_i2;  ca.n4[3] = (int)(sz_i2 / 4);
    ca.src[4] = ffn_w1; ca.dst[4] = w_f1;  ca.n4[4] = (int)(sz_f1 / 4);
    ca.src[5] = ffn_w2; ca.dst[5] = w_f2;  ca.n4[5] = (int)(sz_f2 / 4);
    cvt_all_k<<<dim3(1024), blk, 0, stream>>>(ca);

    // 1. xn = LN(x)
    ln_k<<<dim3(lnGrid), blk, 0, stream>>>(x, lnA_g, lnA_b, bufB, N);
    // 2. qkv = xn @ in_w^T + in_b
    gemm_k<0><<<dim3(18, nrow), gblk, 0, stream>>>(bufB, w_in, in_b, nullptr, bufA, N, 768);
    // 3. attn (2 blocks per head)
    attn_k<<<dim3(1536), blk, 0, stream>>>(bufA, bufB);
    // 4. x1 = x + attn_out @ out_w^T + out_b
    gemm_k<1><<<dim3(6, nrow), gblk, 0, stream>>>(bufB, w_out, out_b, x, x1, N, 768);
    // 5. st = LN(x1)
    ln_k<<<dim3(lnGrid), blk, 0, stream>>>(x1, ln1_g, ln1_b, st, N);
    // 6. INL loop
    for (int it = 0; it < 5; ++it) {
        gemm_k<2><<<dim3(6, nrow), gblk, 0, stream>>>(st, w_i1, inl_b1, nullptr, bufA, N, 768);
        gemm_k<3><<<dim3(6, nrow), gblk, 0, stream>>>(bufA, w_i2, inl_b2, st, st, N, 768);
    }
    // 7. x1 += st; xn2 = LN(x1)
    addln_k<<<dim3(lnGrid), blk, 0, stream>>>(x1, st, ln2_g, ln2_b, bufB, N);
    // 8. h2 = gelu(xn2 @ ffn_w1^T + b1)
    gemm_k<2><<<dim3(24, nrow), gblk, 0, stream>>>(bufB, w_f1, ffn_b1, nullptr, bufA, N, 768);
    // 9. out = x1 + h2 @ ffn_w2^T + b2
    gemm_k<1><<<dim3(6, nrow), gblk, 0, stream>>>(bufA, w_f2, ffn_b2, x1, (float*)d_out, N, 3072);
}

// Round 12
// 740.982 us; speedup vs baseline: 1.1687x; 1.1277x over previous
//
#include <hip/hip_runtime.h>
#include <hip/hip_bf16.h>
#include <cstdio>

// ---------------------------------------------------------------- types
typedef __bf16 bf16x4 __attribute__((ext_vector_type(4)));
typedef __bf16 bf16x8 __attribute__((ext_vector_type(8)));
typedef float  f32x4  __attribute__((ext_vector_type(4)));

#define NTOK 12608   // B*S = 64*197
#define DMODEL 768
#define SEQ 197

__device__ __forceinline__ float b2f(__bf16 v) { return (float)v; }

// fast GELU (tanh form, one v_exp_f32; |err| vs exact erf-GELU < ~3e-4)
__device__ __forceinline__ float gelu_f(float x) {
    float y = 1.5957691216f * (x + 0.044715f * x * x * x);
    float e = __expf(y);
    float t = 1.f - 2.f / (e + 1.f);
    return 0.5f * x * (1.f + t);
}

__device__ __forceinline__ void gload16(const void* src, void* dst) {
    __builtin_amdgcn_global_load_lds(
        (const __attribute__((address_space(1))) void*)src,
        (__attribute__((address_space(3))) void*)dst,
        16, 0, 0);
}

// ---------------------------------------------------------------- f32 -> bf16 convert (all 6 weights, one launch)
struct CvtArgs {
    const float* src[6];
    __bf16* dst[6];
    int n4[6];
};
__global__ __launch_bounds__(256) void cvt_all_k(CvtArgs a)
{
#pragma unroll
    for (int t = 0; t < 6; ++t) {
        const float4* in = (const float4*)a.src[t];
        bf16x4* out = (bf16x4*)a.dst[t];
        const int n4 = a.n4[t];
        for (int i = blockIdx.x * 256 + threadIdx.x; i < n4; i += gridDim.x * 256) {
            float4 v = in[i];
            bf16x4 o;
            o[0] = (__bf16)v.x; o[1] = (__bf16)v.y; o[2] = (__bf16)v.z; o[3] = (__bf16)v.w;
            out[i] = o;
        }
    }
}

// ---------------------------------------------------------------- LayerNorm (f32 in -> bf16 out), 1 wave/row
__global__ __launch_bounds__(256) void ln_k(const float* __restrict__ x,
                                            const float* __restrict__ g,
                                            const float* __restrict__ b,
                                            __bf16* __restrict__ out, int N)
{
    int wid = blockIdx.x * 4 + (threadIdx.x >> 6);
    if (wid >= N) return;
    int lane = threadIdx.x & 63;
    const float4* row = (const float4*)(x + (size_t)wid * DMODEL);
    float v[12];
    float s = 0.f, sq = 0.f;
#pragma unroll
    for (int j = 0; j < 3; ++j) {
        float4 u = row[lane + 64 * j];
        float f0 = u.x, f1 = u.y, f2 = u.z, f3 = u.w;
        v[j*4+0] = f0; v[j*4+1] = f1; v[j*4+2] = f2; v[j*4+3] = f3;
        s += f0 + f1 + f2 + f3;
        sq += f0*f0 + f1*f1 + f2*f2 + f3*f3;
    }
#pragma unroll
    for (int o = 32; o >= 1; o >>= 1) { s += __shfl_xor(s, o); sq += __shfl_xor(sq, o); }
    float mu = s * (1.f / DMODEL);
    float var = sq * (1.f / DMODEL) - mu * mu;
    float rstd = rsqrtf(var + 1e-5f);
    bf16x4* orow = (bf16x4*)(out + (size_t)wid * DMODEL);
    const float4* gg = (const float4*)g;
    const float4* bb = (const float4*)b;
#pragma unroll
    for (int j = 0; j < 3; ++j) {
        float4 gu = gg[lane + 64*j], bu = bb[lane + 64*j];
        bf16x4 o4;
        o4[0] = (__bf16)((v[j*4+0] - mu) * rstd * gu.x + bu.x);
        o4[1] = (__bf16)((v[j*4+1] - mu) * rstd * gu.y + bu.y);
        o4[2] = (__bf16)((v[j*4+2] - mu) * rstd * gu.z + bu.z);
        o4[3] = (__bf16)((v[j*4+3] - mu) * rstd * gu.w + bu.w);
        orow[lane + 64*j] = o4;
    }
}

// x1 (f32, in-place) += st (bf16);  xn2 (bf16) = LN(x1)
__global__ __launch_bounds__(256) void addln_k(float* __restrict__ x1,
                                               const __bf16* __restrict__ st,
                                               const float* __restrict__ g,
                                               const float* __restrict__ b,
                                               __bf16* __restrict__ xn2, int N)
{
    int wid = blockIdx.x * 4 + (threadIdx.x >> 6);
    if (wid >= N) return;
    int lane = threadIdx.x & 63;
    float4* r1 = (float4*)(x1 + (size_t)wid * DMODEL);
    const bf16x4* r2 = (const bf16x4*)(st + (size_t)wid * DMODEL);
    float v[12];
    float s = 0.f, sq = 0.f;
#pragma unroll
    for (int j = 0; j < 3; ++j) {
        float4 u1 = r1[lane + 64*j];
        bf16x4 u2 = r2[lane + 64*j];
        float f0 = u1.x + b2f(u2[0]), f1 = u1.y + b2f(u2[1]);
        float f2 = u1.z + b2f(u2[2]), f3 = u1.w + b2f(u2[3]);
        v[j*4+0] = f0; v[j*4+1] = f1; v[j*4+2] = f2; v[j*4+3] = f3;
        s += f0 + f1 + f2 + f3;
        sq += f0*f0 + f1*f1 + f2*f2 + f3*f3;
        float4 o; o.x = f0; o.y = f1; o.z = f2; o.w = f3;
        r1[lane + 64*j] = o;
    }
#pragma unroll
    for (int o = 32; o >= 1; o >>= 1) { s += __shfl_xor(s, o); sq += __shfl_xor(sq, o); }
    float mu = s * (1.f / DMODEL);
    float var = sq * (1.f / DMODEL) - mu * mu;
    float rstd = rsqrtf(var + 1e-5f);
    bf16x4* on = (bf16x4*)(xn2 + (size_t)wid * DMODEL);
    const float4* gg = (const float4*)g;
    const float4* bb = (const float4*)b;
#pragma unroll
    for (int j = 0; j < 3; ++j) {
        float4 gu = gg[lane + 64*j], bu = bb[lane + 64*j];
        bf16x4 o4;
        o4[0] = (__bf16)((v[j*4+0] - mu) * rstd * gu.x + bu.x);
        o4[1] = (__bf16)((v[j*4+1] - mu) * rstd * gu.y + bu.y);
        o4[2] = (__bf16)((v[j*4+2] - mu) * rstd * gu.z + bu.z);
        o4[3] = (__bf16)((v[j*4+3] - mu) * rstd * gu.w + bu.w);
        on[lane + 64*j] = o4;
    }
}

// ---------------------------------------------------------------- GEMM (64x128 tile): 3 blocks/CU residency variant.
// BM=64, BN=128, BK=64, 512 threads = 8 waves (2 row x 4 col), per-wave
// 32x32 (acc[2][2]). LDS 48 KB -> 3 blocks/CU = 24 waves/CU (vs 2/16 at
// the 128x128 tile) -- resident-block overlap is the proven lever that
// hides the 2-phase barrier drain (r5; m228d: 622 TF at 4 blocks/CU).
// T2 swizzle (conflicts=0): linear LDS dest, source col group ^= row&7,
// read group ^= lr&7 (frag rows == lr mod 8 still holds: wr*32, m*16 == 0 mod 8).
// Sync: verified stage(next) -> MFMA(cur) -> __syncthreads.
// XCD-chunked bijective block swizzle (m204).
// EPI: 0 bf16 v+bias | 1 f32 v+bias+res_f32 | 2 bf16 gelu | 3 bf16 res+0.1v
template <int EPI>
__global__ __launch_bounds__(512) void gemm_k(const __bf16* __restrict__ A,
                                              const __bf16* __restrict__ W,
                                              const float* __restrict__ bias,
                                              const void* __restrict__ resv,
                                              void* __restrict__ outv,
                                              int Nv, int K)
{
    __shared__ __align__(16) __bf16 Al[2][64 * 64];    // 16 KB
    __shared__ __align__(16) __bf16 Bl[2][128 * 64];   // 32 KB
    const int tid = threadIdx.x;
    const int lane = tid & 63;
    const int wv = tid >> 6;              // 0..7
    const int wr = wv >> 2, wc = wv & 3;  // 2 row-waves x 4 col-waves, 32x32 each

    const int ncol = gridDim.x;
    const int nwg = ncol * gridDim.y;
    const int orig = blockIdx.x + ncol * blockIdx.y;
    const int q8 = nwg >> 3, r8 = nwg & 7;
    const int xcd = orig & 7, off8 = orig >> 3;
    const int wgid = (xcd < r8 ? xcd * (q8 + 1) : r8 * (q8 + 1) + (xcd - r8) * q8) + off8;
    const int bcol = (wgid % ncol) * 128;
    const int brow = (wgid / ncol) * 64;

    const int M = ncol * 128;             // ldc
    const int srow = tid >> 3;            // 0..63
    const int scol = (tid & 7) * 8;       // LDS dest col group (linear)
    const int sg = (((tid & 7) ^ (srow & 7)) << 3);   // swizzled source col
    const int lq = lane >> 4, lr = lane & 15;
    const int gsw = lr & 7;               // read-side XOR key

    // A: one staging row per thread (64 rows x 8 col-groups = 512 slots).
    // B: 2 iters x 64 rows. (it*64 + srow) & 7 == srow & 7 -> one sg for all.
    int ar = brow + srow; ar = ar < Nv ? ar : (Nv - 1);
    const __bf16* Arow = A + (size_t)ar * K + sg;
    const __bf16* Wrow[2];
#pragma unroll
    for (int it = 0; it < 2; ++it)
        Wrow[it] = W + (size_t)(bcol + it * 64 + srow) * K + sg;

    f32x4 acc[2][2];
#pragma unroll
    for (int m = 0; m < 2; ++m)
#pragma unroll
        for (int n = 0; n < 2; ++n)
#pragma unroll
            for (int i = 0; i < 4; ++i) acc[m][n][i] = 0.f;

    const int nk = K >> 6;

    // prologue: stage tile 0 into buffer 0 (3 gload_lds per thread)
    gload16(Arow, &Al[0][srow * 64 + scol]);
#pragma unroll
    for (int it = 0; it < 2; ++it)
        gload16(Wrow[it], &Bl[0][(it * 64 + srow) * 64 + scol]);
    __syncthreads();

    for (int t = 0; t < nk; ++t) {
        const int cur = t & 1;
        // stage next tile (overlaps MFMA; trailing __syncthreads drains it)
        if (t + 1 < nk) {
            const int koff = (t + 1) << 6;
            gload16(Arow + koff, &Al[cur ^ 1][srow * 64 + scol]);
#pragma unroll
            for (int it = 0; it < 2; ++it)
                gload16(Wrow[it] + koff, &Bl[cur ^ 1][(it * 64 + srow) * 64 + scol]);
        }
#pragma unroll
        for (int kk = 0; kk < 2; ++kk) {
            bf16x8 af[2], bfr[2];
            const int cg = ((kk * 4 + lq) ^ gsw) << 3;
#pragma unroll
            for (int m = 0; m < 2; ++m)
                af[m] = *(const bf16x8*)&Al[cur][(wr * 32 + m * 16 + lr) * 64 + cg];
#pragma unroll
            for (int n = 0; n < 2; ++n)
                bfr[n] = *(const bf16x8*)&Bl[cur][(wc * 32 + n * 16 + lr) * 64 + cg];
#pragma unroll
            for (int m = 0; m < 2; ++m)
#pragma unroll
                for (int n = 0; n < 2; ++n)
                    acc[m][n] = __builtin_amdgcn_mfma_f32_16x16x32_bf16(af[m], bfr[n], acc[m][n], 0, 0, 0);
        }
        __syncthreads();
    }

#pragma unroll
    for (int m = 0; m < 2; ++m) {
        int row0 = brow + wr * 32 + m * 16 + lq * 4;
#pragma unroll
        for (int n = 0; n < 2; ++n) {
            int col = bcol + wc * 32 + n * 16 + lr;
            float bv = bias[col];
#pragma unroll
            for (int i = 0; i < 4; ++i) {
                int row = row0 + i;
                if (row < Nv) {
                    float v = acc[m][n][i] + bv;
                    size_t off = (size_t)row * M + col;
                    if constexpr (EPI == 0) {
                        ((__bf16*)outv)[off] = (__bf16)v;
                    } else if constexpr (EPI == 1) {
                        ((float*)outv)[off] = v + ((const float*)resv)[off];
                    } else if constexpr (EPI == 2) {
                        ((__bf16*)outv)[off] = (__bf16)gelu_f(v);
                    } else {
                        ((__bf16*)outv)[off] = (__bf16)(b2f(((const __bf16*)resv)[off]) + 0.1f * v);
                    }
                }
            }
        }
    }
}

// ---------------------------------------------------------------- attention: TWO blocks per (b,h) (q-tile split)
__global__ __launch_bounds__(256) void attn_k(const __bf16* __restrict__ qkv,
                                              __bf16* __restrict__ attn_out)
{
    constexpr int S = SEQ, LDP = 232, QKVW = 2304;
    __shared__ __align__(16) __bf16 Vt[64 * LDP];       // [d][j]
    __shared__ __align__(16) __bf16 P[4][16 * LDP];     // per wave [q][j]
    const int bh = blockIdx.x >> 1;
    const int half = blockIdx.x & 1;
    const int b = bh / 12, h = bh % 12;
    const size_t base = (size_t)b * S * QKVW;
    const int tid = threadIdx.x, lane = tid & 63, wv = tid >> 6;
    const int lq = lane >> 4, lr = lane & 15;

    for (int idx = tid; idx < 224 * 8; idx += 256) {
        int j = idx >> 3, d0 = (idx & 7) * 8;
        bf16x8 v8;
        if (j < S) v8 = *(const bf16x8*)(qkv + base + (size_t)j * QKVW + 1536 + h * 64 + d0);
        else {
#pragma unroll
            for (int e = 0; e < 8; ++e) v8[e] = (__bf16)0.f;
        }
#pragma unroll
        for (int e = 0; e < 8; ++e) Vt[(d0 + e) * LDP + j] = v8[e];
    }
    __syncthreads();

    for (int qt = wv + half * 4; qt < 13; qt += 8) {
        int q0 = qt * 16;
        int qrow = q0 + lr; qrow = qrow < S ? qrow : (S - 1);
        bf16x8 aq[2];
#pragma unroll
        for (int kk = 0; kk < 2; ++kk)
            aq[kk] = *(const bf16x8*)(qkv + base + (size_t)qrow * QKVW + h * 64 + kk * 32 + lq * 8);

        f32x4 sc[14];
#pragma unroll
        for (int jf = 0; jf < 14; ++jf) {
#pragma unroll
            for (int i = 0; i < 4; ++i) sc[jf][i] = 0.f;
            int j = jf * 16 + lr; int jc = j < S ? j : (S - 1);
#pragma unroll
            for (int kk = 0; kk < 2; ++kk) {
                bf16x8 bk = *(const bf16x8*)(qkv + base + (size_t)jc * QKVW + 768 + h * 64 + kk * 32 + lq * 8);
                sc[jf] = __builtin_amdgcn_mfma_f32_16x16x32_bf16(aq[kk], bk, sc[jf], 0, 0, 0);
            }
        }
        bool colv[14];
#pragma unroll
        for (int jf = 0; jf < 14; ++jf) colv[jf] = (jf * 16 + lr) < S;
#pragma unroll
        for (int i = 0; i < 4; ++i) {
            float mx = -1.0e30f;
#pragma unroll
            for (int jf = 0; jf < 14; ++jf) {
                float sv = colv[jf] ? sc[jf][i] : -1.0e30f;
                sc[jf][i] = sv;
                mx = fmaxf(mx, sv);
            }
#pragma unroll
            for (int o = 8; o >= 1; o >>= 1) mx = fmaxf(mx, __shfl_xor(mx, o));
            float sm = 0.f;
#pragma unroll
            for (int jf = 0; jf < 14; ++jf) {
                float p = expf((sc[jf][i] - mx) * 0.125f);
                sc[jf][i] = p; sm += p;
            }
#pragma unroll
            for (int o = 8; o >= 1; o >>= 1) sm += __shfl_xor(sm, o);
            float inv = 1.f / sm;
#pragma unroll
            for (int jf = 0; jf < 14; ++jf)
                P[wv][(lq * 4 + i) * LDP + jf * 16 + lr] = (__bf16)(sc[jf][i] * inv);
        }
        f32x4 o4[4];
#pragma unroll
        for (int df = 0; df < 4; ++df)
#pragma unroll
            for (int i = 0; i < 4; ++i) o4[df][i] = 0.f;
#pragma unroll
        for (int ks = 0; ks < 7; ++ks) {
            bf16x8 pa = *(const bf16x8*)&P[wv][lr * LDP + ks * 32 + lq * 8];
#pragma unroll
            for (int df = 0; df < 4; ++df) {
                bf16x8 vb = *(const bf16x8*)&Vt[(df * 16 + lr) * LDP + ks * 32 + lq * 8];
                o4[df] = __builtin_amdgcn_mfma_f32_16x16x32_bf16(pa, vb, o4[df], 0, 0, 0);
            }
        }
#pragma unroll
        for (int df = 0; df < 4; ++df)
#pragma unroll
            for (int i = 0; i < 4; ++i) {
                int qr = q0 + lq * 4 + i;
                if (qr < S)
                    attn_out[((size_t)b * S + qr) * DMODEL + h * 64 + df * 16 + lr] = (__bf16)o4[df][i];
            }
    }
}

// ---------------------------------------------------------------- launch
extern "C" void kernel_launch(void* const* d_in, const int* in_sizes, int n_in,
                              void* d_out, int out_size, void* d_ws, size_t ws_size,
                              hipStream_t stream) {
    const float* x      = (const float*)d_in[0];
    const float* in_w   = (const float*)d_in[1];
    const float* in_b   = (const float*)d_in[2];
    const float* out_w  = (const float*)d_in[3];
    const float* out_b  = (const float*)d_in[4];
    const float* lnA_g  = (const float*)d_in[5];
    const float* lnA_b  = (const float*)d_in[6];
    const float* ln1_g  = (const float*)d_in[7];
    const float* ln1_b  = (const float*)d_in[8];
    const float* ln2_g  = (const float*)d_in[9];
    const float* ln2_b  = (const float*)d_in[10];
    const float* inl_w1 = (const float*)d_in[11];
    const float* inl_b1 = (const float*)d_in[12];
    const float* inl_w2 = (const float*)d_in[13];
    const float* inl_b2 = (const float*)d_in[14];
    const float* ffn_w1 = (const float*)d_in[15];
    const float* ffn_b1 = (const float*)d_in[16];
    const float* ffn_w2 = (const float*)d_in[17];
    const float* ffn_b2 = (const float*)d_in[18];

    const int N = NTOK;
    const size_t sz_inw = (size_t)2304 * 768, sz_outw = (size_t)768 * 768;
    const size_t sz_i1 = (size_t)768 * 768, sz_i2 = (size_t)768 * 768;
    const size_t sz_f1 = (size_t)3072 * 768, sz_f2 = (size_t)768 * 3072;
    const size_t wtot = sz_inw + sz_outw + sz_i1 + sz_i2 + sz_f1 + sz_f2;

    const size_t bA = (size_t)N * 3072 * 2;
    const size_t bB = (size_t)N * 768 * 2;
    const size_t bS = (size_t)N * 768 * 2;
    const size_t bX = (size_t)N * 768 * 4;
    const size_t need = wtot * 2 + bA + bB + bS + bX;
    if (ws_size < need) {
        fprintf(stderr, "kernel_launch: ws_size %zu < required %zu\n", ws_size, need);
        return;
    }
    char* ws = (char*)d_ws;
    __bf16* w_in  = (__bf16*)ws;
    __bf16* w_out = w_in + sz_inw;
    __bf16* w_i1  = w_out + sz_outw;
    __bf16* w_i2  = w_i1 + sz_i1;
    __bf16* w_f1  = w_i2 + sz_i2;
    __bf16* w_f2  = w_f1 + sz_f1;
    char* p = ws + wtot * 2;
    __bf16* bufA = (__bf16*)p;            p += bA;
    __bf16* bufB = (__bf16*)p;            p += bB;
    __bf16* st   = (__bf16*)p;            p += bS;
    float*  x1   = (float*)p;

    dim3 blk(256), gblk(512);
    const int lnGrid = (N + 3) / 4;
    const int nrow = 197;  // 12608 / 64 (exact)

    CvtArgs ca;
    ca.src[0] = in_w;   ca.dst[0] = w_in;  ca.n4[0] = (int)(sz_inw / 4);
    ca.src[1] = out_w;  ca.dst[1] = w_out; ca.n4[1] = (int)(sz_outw / 4);
    ca.src[2] = inl_w1; ca.dst[2] = w_i1;  ca.n4[2] = (int)(sz_i1 / 4);
    ca.src[3] = inl_w2; ca.dst[3] = w_i2;  ca.n4[3] = (int)(sz_i2 / 4);
    ca.src[4] = ffn_w1; ca.dst[4] = w_f1;  ca.n4[4] = (int)(sz_f1 / 4);
    ca.src[5] = ffn_w2; ca.dst[5] = w_f2;  ca.n4[5] = (int)(sz_f2 / 4);
    cvt_all_k<<<dim3(1024), blk, 0, stream>>>(ca);

    // 1. xn = LN(x)
    ln_k<<<dim3(lnGrid), blk, 0, stream>>>(x, lnA_g, lnA_b, bufB, N);
    // 2. qkv = xn @ in_w^T + in_b
    gemm_k<0><<<dim3(18, nrow), gblk, 0, stream>>>(bufB, w_in, in_b, nullptr, bufA, N, 768);
    // 3. attn (2 blocks per head)
    attn_k<<<dim3(1536), blk, 0, stream>>>(bufA, bufB);
    // 4. x1 = x + attn_out @ out_w^T + out_b
    gemm_k<1><<<dim3(6, nrow), gblk, 0, stream>>>(bufB, w_out, out_b, x, x1, N, 768);
    // 5. st = LN(x1)
    ln_k<<<dim3(lnGrid), blk, 0, stream>>>(x1, ln1_g, ln1_b, st, N);
    // 6. INL loop
    for (int it = 0; it < 5; ++it) {
        gemm_k<2><<<dim3(6, nrow), gblk, 0, stream>>>(st, w_i1, inl_b1, nullptr, bufA, N, 768);
        gemm_k<3><<<dim3(6, nrow), gblk, 0, stream>>>(bufA, w_i2, inl_b2, st, st, N, 768);
    }
    // 7. x1 += st; xn2 = LN(x1)
    addln_k<<<dim3(lnGrid), blk, 0, stream>>>(x1, st, ln2_g, ln2_b, bufB, N);
    // 8. h2 = gelu(xn2 @ ffn_w1^T + b1)
    gemm_k<2><<<dim3(24, nrow), gblk, 0, stream>>>(bufB, w_f1, ffn_b1, nullptr, bufA, N, 768);
    // 9. out = x1 + h2 @ ffn_w2^T + b2
    gemm_k<1><<<dim3(6, nrow), gblk, 0, stream>>>(bufA, w_f2, ffn_b2, x1, (float*)d_out, N, 3072);
}